// Round 1
// baseline (594.217 us; speedup 1.0000x reference)
//
#include <hip/hip_runtime.h>
#include <cstdint>
#include <math.h>

#define L_SEQ 8192
#define DM    1024

typedef unsigned short u16;
typedef __bf16 bf16;
typedef bf16  bf16x8 __attribute__((ext_vector_type(8)));
typedef float f32x4  __attribute__((ext_vector_type(4)));

__device__ __forceinline__ u16 f2bf(float f) {
    unsigned u = __float_as_uint(f);
    u += 0x7fffu + ((u >> 16) & 1u);
    return (u16)(u >> 16);
}

__device__ __forceinline__ f32x4 mfma16(bf16x8 a, bf16x8 b, f32x4 c) {
    return __builtin_amdgcn_mfma_f32_16x16x32_bf16(a, b, c, 0, 0, 0);
}

__device__ __forceinline__ void gld_lds16(const u16* g, u16* l) {
    __builtin_amdgcn_global_load_lds((const __attribute__((address_space(1))) void*)g,
                                     (__attribute__((address_space(3))) void*)l,
                                     16, 0, 0);
}

// ---------------- fp32 -> bf16 conversion (8 elems / thread) ----------------
__global__ void cvt_bf16(const float* __restrict__ src, u16* __restrict__ dst, int n8) {
    int i = blockIdx.x * 256 + threadIdx.x;
    if (i >= n8) return;
    const float4* s4 = (const float4*)src;
    float4 a = s4[2 * i], b = s4[2 * i + 1];
    union { uint4 u; u16 h[8]; } r;
    r.h[0] = f2bf(a.x); r.h[1] = f2bf(a.y); r.h[2] = f2bf(a.z); r.h[3] = f2bf(a.w);
    r.h[4] = f2bf(b.x); r.h[5] = f2bf(b.y); r.h[6] = f2bf(b.z); r.h[7] = f2bf(b.w);
    ((uint4*)dst)[i] = r.u;
}

// ---------------- QKV GEMM: Y = X * W^T, optional fused RoPE, bf16 out ------
// 128x128 tile, BK=32, 4 waves (2x2 of 64x64), global_load_lds staging.
__global__ __launch_bounds__(256) void gemm_qkv(
    const u16* __restrict__ X,
    const u16* __restrict__ Wq, const u16* __restrict__ Wk, const u16* __restrict__ Wv,
    u16* __restrict__ Qo, u16* __restrict__ Ko, u16* __restrict__ Vo)
{
    __shared__ __align__(16) char smem[34816];   // staging (16KB) aliased with epilogue tile (34.8KB)
    u16* As = (u16*)smem;          // [128][32]
    u16* Bs = As + 128 * 32;       // [128][32]

    const int z = blockIdx.z;
    const u16* W = (z == 0) ? Wq : ((z == 1) ? Wk : Wv);
    u16* O       = (z == 0) ? Qo : ((z == 1) ? Ko : Vo);

    const int m0 = blockIdx.x * 128;
    const int n0 = blockIdx.y * 128;
    const int tid = threadIdx.x;
    const int lane = tid & 63, wid = tid >> 6;
    const int wm = wid >> 1, wn = wid & 1;
    const int quad = lane >> 4, ln = lane & 15;

    const f32x4 fz = {0.f, 0.f, 0.f, 0.f};
    f32x4 acc[4][4];
    for (int a = 0; a < 4; a++)
        for (int b = 0; b < 4; b++) acc[a][b] = fz;

    for (int k0 = 0; k0 < DM; k0 += 32) {
        __syncthreads();
        #pragma unroll
        for (int i = 0; i < 2; ++i) {
            int idx = i * 256 + tid;
            int row = idx >> 2, ch = (idx & 3) * 8;
            gld_lds16(X + (size_t)(m0 + row) * DM + k0 + ch, As + idx * 8);
            gld_lds16(W + (size_t)(n0 + row) * DM + k0 + ch, Bs + idx * 8);
        }
        __syncthreads();
        bf16x8 af[4], bfr[4];
        #pragma unroll
        for (int t = 0; t < 4; t++) {
            af[t]  = *(const bf16x8*)(As + (wm * 64 + t * 16 + ln) * 32 + quad * 8);
            bfr[t] = *(const bf16x8*)(Bs + (wn * 64 + t * 16 + ln) * 32 + quad * 8);
        }
        #pragma unroll
        for (int mt = 0; mt < 4; mt++)
            #pragma unroll
            for (int nt = 0; nt < 4; nt++)
                acc[mt][nt] = mfma16(af[mt], bfr[nt], acc[mt][nt]);
    }
    __syncthreads();   // all LDS frag reads done before epilogue overwrites smem

    if (z < 2) {
        // Fused RoPE. Wave covers exactly one head's 64 cols (n0,wn are 64-aligned).
        // Pair (dh, dh+32) = acc tiles (nt, nt+2), same lane/reg.
        #pragma unroll
        for (int mt = 0; mt < 4; mt++)
            #pragma unroll
            for (int reg = 0; reg < 4; reg++) {
                int rg = m0 + wm * 64 + mt * 16 + quad * 4 + reg;
                float pos = (float)(rg & (L_SEQ - 1));
                #pragma unroll
                for (int nt = 0; nt < 2; nt++) {
                    int i = nt * 16 + ln;                       // 0..31
                    float invf = exp2f(-0.4152410118609191f * (float)i); // 10000^(-i/32)
                    float ang = pos * invf;
                    float sv, cv;
                    sincosf(ang, &sv, &cv);
                    float x1 = acc[mt][nt][reg], x2 = acc[mt][nt + 2][reg];
                    acc[mt][nt][reg]     = x1 * cv - x2 * sv;
                    acc[mt][nt + 2][reg] = x2 * cv + x1 * sv;
                }
            }
    }

    // Epilogue: bf16 tile through LDS for coalesced 16B stores
    u16* Es = (u16*)smem;   // [128][136]
    #pragma unroll
    for (int mt = 0; mt < 4; mt++)
        #pragma unroll
        for (int nt = 0; nt < 4; nt++)
            #pragma unroll
            for (int reg = 0; reg < 4; reg++) {
                int rl = wm * 64 + mt * 16 + quad * 4 + reg;
                int cl = wn * 64 + nt * 16 + ln;
                Es[rl * 136 + cl] = f2bf(acc[mt][nt][reg]);
            }
    __syncthreads();
    #pragma unroll
    for (int i = 0; i < 8; i++) {
        int idx = i * 256 + tid;
        int row = idx >> 4, ch = (idx & 15) * 8;
        uint4 v = *(const uint4*)(Es + row * 136 + ch);
        *(uint4*)(O + (size_t)(m0 + row) * DM + n0 + ch) = v;
    }
}

// ---------------- Output projection: Out = A * Wo^T + bo, fp32 out ----------
__global__ __launch_bounds__(256) void gemm_oproj(
    const u16* __restrict__ A,
    const u16* __restrict__ Wo,
    const float* __restrict__ bias,
    float* __restrict__ Out)
{
    __shared__ __align__(16) char smem[34816];
    u16* As = (u16*)smem;
    u16* Bs = As + 128 * 32;

    const int m0 = blockIdx.x * 128;
    const int n0 = blockIdx.y * 128;
    const int tid = threadIdx.x;
    const int lane = tid & 63, wid = tid >> 6;
    const int wm = wid >> 1, wn = wid & 1;
    const int quad = lane >> 4, ln = lane & 15;

    const f32x4 fz = {0.f, 0.f, 0.f, 0.f};
    f32x4 acc[4][4];
    for (int a = 0; a < 4; a++)
        for (int b = 0; b < 4; b++) acc[a][b] = fz;

    for (int k0 = 0; k0 < DM; k0 += 32) {
        __syncthreads();
        #pragma unroll
        for (int i = 0; i < 2; ++i) {
            int idx = i * 256 + tid;
            int row = idx >> 2, ch = (idx & 3) * 8;
            gld_lds16(A  + (size_t)(m0 + row) * DM + k0 + ch, As + idx * 8);
            gld_lds16(Wo + (size_t)(n0 + row) * DM + k0 + ch, Bs + idx * 8);
        }
        __syncthreads();
        bf16x8 af[4], bfr[4];
        #pragma unroll
        for (int t = 0; t < 4; t++) {
            af[t]  = *(const bf16x8*)(As + (wm * 64 + t * 16 + ln) * 32 + quad * 8);
            bfr[t] = *(const bf16x8*)(Bs + (wn * 64 + t * 16 + ln) * 32 + quad * 8);
        }
        #pragma unroll
        for (int mt = 0; mt < 4; mt++)
            #pragma unroll
            for (int nt = 0; nt < 4; nt++)
                acc[mt][nt] = mfma16(af[mt], bfr[nt], acc[mt][nt]);
    }

    // fp32 epilogue via LDS, two 64-row halves (64*136*4 = 34816 B each pass)
    float* Ef = (float*)smem;
    for (int hh = 0; hh < 2; ++hh) {
        __syncthreads();
        if (wm == hh) {
            #pragma unroll
            for (int mt = 0; mt < 4; mt++)
                #pragma unroll
                for (int nt = 0; nt < 4; nt++)
                    #pragma unroll
                    for (int reg = 0; reg < 4; reg++) {
                        int rl = mt * 16 + quad * 4 + reg;       // 0..63
                        int cl = wn * 64 + nt * 16 + ln;
                        Ef[rl * 136 + cl] = acc[mt][nt][reg] + bias[n0 + cl];
                    }
        }
        __syncthreads();
        #pragma unroll
        for (int i = 0; i < 8; i++) {
            int idx = i * 256 + tid;
            int row = idx >> 5, ch = (idx & 31) * 4;
            float4 v = *(const float4*)(Ef + row * 136 + ch);
            *(float4*)(Out + (size_t)(m0 + hh * 64 + row) * DM + n0 + ch) = v;
        }
    }
}

// ---------------- Windowed attention ----------------------------------------
// grid (128, 16, 2): x = blk*2 + half (64 queries/WG), y = head, z = batch.
// Wave handles 16 queries x 256 keys via MFMA; softmax in registers (C-layout),
// P relayout through 1KB/wave LDS chunk, PV against LDS-transposed V.
__global__ __launch_bounds__(256) void attn(
    const u16* __restrict__ Q, const u16* __restrict__ K, const u16* __restrict__ V,
    u16* __restrict__ AO)
{
    __shared__ __align__(16) u16 vT[64 * 264];       // V^T, pad stride 264
    __shared__ __align__(16) u16 pbuf[4][16 * 32];   // per-wave P chunk

    const int bx = blockIdx.x;
    const int h  = blockIdx.y;
    const int b  = blockIdx.z;
    const int blk = bx >> 1, half = bx & 1;
    const int tid = threadIdx.x;
    const int lane = tid & 63, w = tid >> 6;
    const int quad = lane >> 4, ln = lane & 15;
    const int wstart = blk * 128 - 64;
    const size_t bbase = (size_t)b * L_SEQ;

    // stage V^T (invalid rows clamped; they get zero attention weight)
    #pragma unroll
    for (int i = 0; i < 8; i++) {
        int c = i * 256 + tid;                 // 2048 chunks of 8 bf16
        int key = c >> 3, db = (c & 7) * 8;
        int kr = wstart + key;
        kr = kr < 0 ? 0 : (kr > L_SEQ - 1 ? L_SEQ - 1 : kr);
        uint4 raw = *(const uint4*)(V + (bbase + kr) * DM + h * 64 + db);
        union { uint4 u; u16 s[8]; } t; t.u = raw;
        #pragma unroll
        for (int j = 0; j < 8; j++) vT[(db + j) * 264 + key] = t.s[j];
    }

    // Q fragments (A-layout: m=ln, k=quad*8+j), direct from global
    const int qrow = blk * 128 + half * 64 + w * 16 + ln;
    const u16* qp = Q + (bbase + qrow) * DM + h * 64 + quad * 8;
    bf16x8 aq0 = *(const bf16x8*)qp;
    bf16x8 aq1 = *(const bf16x8*)(qp + 32);
    __syncthreads();

    // scores: 16 n-tiles of 16 keys, K=64 in 2 MFMA steps
    const f32x4 fz = {0.f, 0.f, 0.f, 0.f};
    f32x4 s[16];
    #pragma unroll
    for (int nt = 0; nt < 16; nt++) {
        int kr = wstart + nt * 16 + ln;
        kr = kr < 0 ? 0 : (kr > L_SEQ - 1 ? L_SEQ - 1 : kr);
        const u16* kp = K + (bbase + kr) * DM + h * 64 + quad * 8;
        bf16x8 b0 = *(const bf16x8*)kp;
        bf16x8 b1 = *(const bf16x8*)(kp + 32);
        f32x4 t = mfma16(aq0, b0, fz);
        t = mfma16(aq1, b1, t);
        s[nt] = t;
    }

    // softmax over 256 keys; row = quad*4 + reg, col = nt*16 + ln
    float mr[4] = {-INFINITY, -INFINITY, -INFINITY, -INFINITY};
    #pragma unroll
    for (int nt = 0; nt < 16; nt++) {
        int key = wstart + nt * 16 + ln;
        bool valid = (key >= 0) && (key < L_SEQ);
        #pragma unroll
        for (int r = 0; r < 4; r++) {
            float v = valid ? s[nt][r] * 0.125f : -INFINITY;
            s[nt][r] = v;
            mr[r] = fmaxf(mr[r], v);
        }
    }
    #pragma unroll
    for (int off = 1; off < 16; off <<= 1)
        #pragma unroll
        for (int r = 0; r < 4; r++) mr[r] = fmaxf(mr[r], __shfl_xor(mr[r], off));

    float lr[4] = {0.f, 0.f, 0.f, 0.f};
    #pragma unroll
    for (int nt = 0; nt < 16; nt++)
        #pragma unroll
        for (int r = 0; r < 4; r++) {
            float p = expf(s[nt][r] - mr[r]);   // exp(-inf) = 0 on masked cols
            s[nt][r] = p;
            lr[r] += p;
        }
    #pragma unroll
    for (int off = 1; off < 16; off <<= 1)
        #pragma unroll
        for (int r = 0; r < 4; r++) lr[r] += __shfl_xor(lr[r], off);
    float rl[4];
    #pragma unroll
    for (int r = 0; r < 4; r++) rl[r] = 1.f / lr[r];

    // PV: per 32-key chunk, C-layout -> A-layout via per-wave LDS round-trip
    u16* pb = pbuf[w];
    f32x4 o[4] = {fz, fz, fz, fz};
    #pragma unroll
    for (int ks = 0; ks < 8; ks++) {
        #pragma unroll
        for (int n2 = 0; n2 < 2; n2++) {
            int nt = ks * 2 + n2;
            #pragma unroll
            for (int r = 0; r < 4; r++)
                pb[(quad * 4 + r) * 32 + n2 * 16 + ln] = f2bf(s[nt][r]);
        }
        bf16x8 ap = *(const bf16x8*)(pb + ln * 32 + quad * 8);
        #pragma unroll
        for (int dt = 0; dt < 4; dt++) {
            bf16x8 vb = *(const bf16x8*)(vT + (dt * 16 + ln) * 264 + ks * 32 + quad * 8);
            o[dt] = mfma16(ap, vb, o[dt]);
        }
    }

    // store O (row = quad*4+reg), normalized by row sum
    const int orow = blk * 128 + half * 64 + w * 16 + quad * 4;
    #pragma unroll
    for (int dt = 0; dt < 4; dt++)
        #pragma unroll
        for (int r = 0; r < 4; r++)
            AO[(bbase + orow + r) * DM + h * 64 + dt * 16 + ln] = f2bf(o[dt][r] * rl[r]);
}

// ---------------------------------------------------------------------------
extern "C" void kernel_launch(void* const* d_in, const int* in_sizes, int n_in,
                              void* d_out, int out_size, void* d_ws, size_t ws_size,
                              hipStream_t stream) {
    const float* x  = (const float*)d_in[0];
    const float* wq = (const float*)d_in[1];
    const float* wk = (const float*)d_in[2];
    const float* wv = (const float*)d_in[3];
    const float* wo = (const float*)d_in[4];
    const float* bo = (const float*)d_in[5];
    float* out = (float*)d_out;

    char* ws = (char*)d_ws;
    const size_t SB = (size_t)16384 * 1024 * 2;   // 33,554,432 B per bf16 activation buf
    u16* xb  = (u16*)ws;
    u16* qb  = (u16*)(ws + SB);
    u16* kb  = (u16*)(ws + 2 * SB);
    u16* vb  = (u16*)(ws + 3 * SB);
    u16* wqb = (u16*)(ws + 4 * SB);
    u16* wkb = (u16*)(ws + 4 * SB + 1 * 2097152);
    u16* wvb = (u16*)(ws + 4 * SB + 2 * 2097152);
    u16* wob = (u16*)(ws + 4 * SB + 3 * 2097152);
    u16* aob = xb;   // x dead after qkv GEMMs; alias attention output over it

    cvt_bf16<<<8192, 256, 0, stream>>>(x, xb, 2097152);
    cvt_bf16<<<512, 256, 0, stream>>>(wq, wqb, 131072);
    cvt_bf16<<<512, 256, 0, stream>>>(wk, wkb, 131072);
    cvt_bf16<<<512, 256, 0, stream>>>(wv, wvb, 131072);
    cvt_bf16<<<512, 256, 0, stream>>>(wo, wob, 131072);

    gemm_qkv<<<dim3(128, 8, 3), 256, 0, stream>>>(xb, wqb, wkb, wvb, qb, kb, vb);
    attn<<<dim3(128, 16, 2), 256, 0, stream>>>(qb, kb, vb, aob);
    gemm_oproj<<<dim3(128, 8), 256, 0, stream>>>(aob, wob, bo, out);
}

// Round 2
// 443.423 us; speedup vs baseline: 1.3401x; 1.3401x over previous
//
#include <hip/hip_runtime.h>
#include <cstdint>
#include <math.h>

#define L_SEQ 8192
#define DM    1024
#define NF    3072          // fused QKV output width

typedef unsigned short u16;
typedef __bf16 bf16;
typedef bf16  bf16x8 __attribute__((ext_vector_type(8)));
typedef float f32x4  __attribute__((ext_vector_type(4)));

__device__ __forceinline__ u16 f2bf(float f) {
    unsigned u = __float_as_uint(f);
    u += 0x7fffu + ((u >> 16) & 1u);
    return (u16)(u >> 16);
}

__device__ __forceinline__ f32x4 mfma16(bf16x8 a, bf16x8 b, f32x4 c) {
    return __builtin_amdgcn_mfma_f32_16x16x32_bf16(a, b, c, 0, 0, 0);
}

__device__ __forceinline__ void gld_lds16(const u16* g, u16* l) {
    __builtin_amdgcn_global_load_lds((const __attribute__((address_space(1))) void*)g,
                                     (__attribute__((address_space(3))) void*)l,
                                     16, 0, 0);
}

// ---------------- fp32 -> bf16 conversion (8 elems / thread) ----------------
__global__ void cvt_bf16(const float* __restrict__ src, u16* __restrict__ dst, int n8) {
    int i = blockIdx.x * 256 + threadIdx.x;
    if (i >= n8) return;
    const float4* s4 = (const float4*)src;
    float4 a = s4[2 * i], b = s4[2 * i + 1];
    union { uint4 u; u16 h[8]; } r;
    r.h[0] = f2bf(a.x); r.h[1] = f2bf(a.y); r.h[2] = f2bf(a.z); r.h[3] = f2bf(a.w);
    r.h[4] = f2bf(b.x); r.h[5] = f2bf(b.y); r.h[6] = f2bf(b.z); r.h[7] = f2bf(b.w);
    ((uint4*)dst)[i] = r.u;
}

// ---------------- RoPE cos/sin table: [8192 pos][32 freq] float2 ------------
__global__ void rope_tbl(float2* __restrict__ t) {
    int idx = blockIdx.x * 256 + threadIdx.x;      // 0..262143
    int pos = idx >> 5, i = idx & 31;
    float invf = exp2f(-0.4152410118609191f * (float)i);   // 10000^(-i/32)
    float s, c;
    sincosf((float)pos * invf, &s, &c);
    t[idx] = make_float2(c, s);
}

// ---------------- Fused QKV GEMM: Y[16384][3072] = X * Wqkv^T ---------------
// 128x128 tile, BK=64, XOR-swizzled LDS (conflict-free ds_read_b128),
// global_load_lds staging, RoPE (table-based) fused for the Q/K column range.
__global__ __launch_bounds__(256) void gemm_qkv_fused(
    const u16* __restrict__ X,        // [16384][1024]
    const u16* __restrict__ W,        // [3072][1024]  rows: 0..1023 q, 1024..2047 k, 2048.. v
    const float2* __restrict__ rope,  // [8192][32]
    u16* __restrict__ Y)              // [16384][3072]
{
    __shared__ __align__(16) char smem[34816];  // staging 32KB aliased w/ 34.8KB epilogue
    u16* As = (u16*)smem;          // [128][64] swizzled
    u16* Bs = As + 128 * 64;       // [128][64] swizzled

    const int m0 = blockIdx.x * 128;
    const int n0 = blockIdx.y * 128;
    const int tid = threadIdx.x;
    const int lane = tid & 63, wid = tid >> 6;
    const int wm = wid >> 1, wn = wid & 1;
    const int quad = lane >> 4, ln = lane & 15;

    const f32x4 fz = {0.f, 0.f, 0.f, 0.f};
    f32x4 acc[4][4];
    for (int a = 0; a < 4; a++)
        for (int b = 0; b < 4; b++) acc[a][b] = fz;

    for (int k0 = 0; k0 < DM; k0 += 64) {
        __syncthreads();
        #pragma unroll
        for (int i = 0; i < 4; ++i) {
            int idx = i * 256 + tid;
            int row = idx >> 3, cl = idx & 7;
            int cg = cl ^ (row & 7);              // source chunk permutation = LDS XOR swizzle
            gld_lds16(X + (size_t)(m0 + row) * DM + k0 + cg * 8, As + idx * 8);
            gld_lds16(W + (size_t)(n0 + row) * DM + k0 + cg * 8, Bs + idx * 8);
        }
        __syncthreads();
        #pragma unroll
        for (int ks = 0; ks < 2; ks++) {
            bf16x8 af[4], bfr[4];
            #pragma unroll
            for (int t = 0; t < 4; t++) {
                int ra = wm * 64 + t * 16 + ln;
                af[t]  = *(const bf16x8*)(As + ra * 64 + (((ks * 4 + quad) ^ (ln & 7)) * 8));
                int rb = wn * 64 + t * 16 + ln;
                bfr[t] = *(const bf16x8*)(Bs + rb * 64 + (((ks * 4 + quad) ^ (ln & 7)) * 8));
            }
            #pragma unroll
            for (int mt = 0; mt < 4; mt++)
                #pragma unroll
                for (int nt = 0; nt < 4; nt++)
                    acc[mt][nt] = mfma16(af[mt], bfr[nt], acc[mt][nt]);
        }
    }
    __syncthreads();   // all LDS frag reads done before epilogue overwrites smem

    if (n0 < 2048) {
        // RoPE via table. Wave covers one head's 64 cols; pair (i, i+32) = tiles (nt, nt+2).
        #pragma unroll
        for (int mt = 0; mt < 4; mt++)
            #pragma unroll
            for (int reg = 0; reg < 4; reg++) {
                int rg = (m0 + wm * 64 + mt * 16 + quad * 4 + reg) & (L_SEQ - 1);
                const float2* rp = rope + rg * 32;
                #pragma unroll
                for (int nt = 0; nt < 2; nt++) {
                    float2 cs = rp[nt * 16 + ln];
                    float x1 = acc[mt][nt][reg], x2 = acc[mt][nt + 2][reg];
                    acc[mt][nt][reg]     = x1 * cs.x - x2 * cs.y;
                    acc[mt][nt + 2][reg] = x2 * cs.x + x1 * cs.y;
                }
            }
    }

    // Epilogue: bf16 tile through LDS for coalesced 16B stores
    u16* Es = (u16*)smem;   // [128][136]
    #pragma unroll
    for (int mt = 0; mt < 4; mt++)
        #pragma unroll
        for (int nt = 0; nt < 4; nt++)
            #pragma unroll
            for (int reg = 0; reg < 4; reg++) {
                int rl = wm * 64 + mt * 16 + quad * 4 + reg;
                int cl = wn * 64 + nt * 16 + ln;
                Es[rl * 136 + cl] = f2bf(acc[mt][nt][reg]);
            }
    __syncthreads();
    #pragma unroll
    for (int i = 0; i < 8; i++) {
        int idx = i * 256 + tid;
        int row = idx >> 4, ch = (idx & 15) * 8;
        uint4 v = *(const uint4*)(Es + row * 136 + ch);
        *(uint4*)(Y + (size_t)(m0 + row) * NF + n0 + ch) = v;
    }
}

// ---------------- Output projection: Out = A * Wo^T + bo, fp32 out ----------
__global__ __launch_bounds__(256) void gemm_oproj(
    const u16* __restrict__ A,        // [16384][1024] bf16
    const u16* __restrict__ Wo,       // [1024][1024] bf16
    const float* __restrict__ bias,
    float* __restrict__ Out)
{
    __shared__ __align__(16) char smem[34816];
    u16* As = (u16*)smem;
    u16* Bs = As + 128 * 64;

    const int m0 = blockIdx.x * 128;
    const int n0 = blockIdx.y * 128;
    const int tid = threadIdx.x;
    const int lane = tid & 63, wid = tid >> 6;
    const int wm = wid >> 1, wn = wid & 1;
    const int quad = lane >> 4, ln = lane & 15;

    const f32x4 fz = {0.f, 0.f, 0.f, 0.f};
    f32x4 acc[4][4];
    for (int a = 0; a < 4; a++)
        for (int b = 0; b < 4; b++) acc[a][b] = fz;

    for (int k0 = 0; k0 < DM; k0 += 64) {
        __syncthreads();
        #pragma unroll
        for (int i = 0; i < 4; ++i) {
            int idx = i * 256 + tid;
            int row = idx >> 3, cl = idx & 7;
            int cg = cl ^ (row & 7);
            gld_lds16(A  + (size_t)(m0 + row) * DM + k0 + cg * 8, As + idx * 8);
            gld_lds16(Wo + (size_t)(n0 + row) * DM + k0 + cg * 8, Bs + idx * 8);
        }
        __syncthreads();
        #pragma unroll
        for (int ks = 0; ks < 2; ks++) {
            bf16x8 af[4], bfr[4];
            #pragma unroll
            for (int t = 0; t < 4; t++) {
                int ra = wm * 64 + t * 16 + ln;
                af[t]  = *(const bf16x8*)(As + ra * 64 + (((ks * 4 + quad) ^ (ln & 7)) * 8));
                int rb = wn * 64 + t * 16 + ln;
                bfr[t] = *(const bf16x8*)(Bs + rb * 64 + (((ks * 4 + quad) ^ (ln & 7)) * 8));
            }
            #pragma unroll
            for (int mt = 0; mt < 4; mt++)
                #pragma unroll
                for (int nt = 0; nt < 4; nt++)
                    acc[mt][nt] = mfma16(af[mt], bfr[nt], acc[mt][nt]);
        }
    }

    // fp32 epilogue via LDS, two 64-row halves
    float* Ef = (float*)smem;
    for (int hh = 0; hh < 2; ++hh) {
        __syncthreads();
        if (wm == hh) {
            #pragma unroll
            for (int mt = 0; mt < 4; mt++)
                #pragma unroll
                for (int nt = 0; nt < 4; nt++)
                    #pragma unroll
                    for (int reg = 0; reg < 4; reg++) {
                        int rl = mt * 16 + quad * 4 + reg;
                        int cl = wn * 64 + nt * 16 + ln;
                        Ef[rl * 136 + cl] = acc[mt][nt][reg] + bias[n0 + cl];
                    }
        }
        __syncthreads();
        #pragma unroll
        for (int i = 0; i < 8; i++) {
            int idx = i * 256 + tid;
            int row = idx >> 5, ch = (idx & 31) * 4;
            float4 v = *(const float4*)(Ef + row * 136 + ch);
            *(float4*)(Out + (size_t)(m0 + hh * 64 + row) * DM + n0 + ch) = v;
        }
    }
}

// ---------------- Windowed attention ----------------------------------------
// Reads Q/K/V from fused layout (row stride 3072; K at +1024, V at +2048).
// grid (128, 16, 2): x = blk*2 + half (64 queries/WG), y = head, z = batch.
__global__ __launch_bounds__(256) void attn(
    const u16* __restrict__ F,        // fused QKV [16384][3072]
    u16* __restrict__ AO)             // [16384][1024]
{
    __shared__ __align__(16) u16 vT[64 * 264];       // V^T, pad stride 264
    __shared__ __align__(16) u16 pbuf[4][16 * 32];   // per-wave P chunk

    const int bx = blockIdx.x;
    const int h  = blockIdx.y;
    const int b  = blockIdx.z;
    const int blk = bx >> 1, half = bx & 1;
    const int tid = threadIdx.x;
    const int lane = tid & 63, w = tid >> 6;
    const int quad = lane >> 4, ln = lane & 15;
    const int wstart = blk * 128 - 64;
    const size_t bbase = (size_t)b * L_SEQ;

    // stage V^T (invalid rows clamped; they get zero attention weight)
    #pragma unroll
    for (int i = 0; i < 8; i++) {
        int c = i * 256 + tid;                 // 2048 chunks of 8 bf16
        int key = c >> 3, db = (c & 7) * 8;
        int kr = wstart + key;
        kr = kr < 0 ? 0 : (kr > L_SEQ - 1 ? L_SEQ - 1 : kr);
        uint4 raw = *(const uint4*)(F + (bbase + kr) * NF + 2048 + h * 64 + db);
        union { uint4 u; u16 s[8]; } t; t.u = raw;
        #pragma unroll
        for (int j = 0; j < 8; j++) vT[(db + j) * 264 + key] = t.s[j];
    }

    // Q fragments (A-layout: m=ln, k=quad*8+j), direct from global
    const int qrow = blk * 128 + half * 64 + w * 16 + ln;
    const u16* qp = F + (bbase + qrow) * NF + h * 64 + quad * 8;
    bf16x8 aq0 = *(const bf16x8*)qp;
    bf16x8 aq1 = *(const bf16x8*)(qp + 32);
    __syncthreads();

    // scores: 16 n-tiles of 16 keys, K=64 in 2 MFMA steps
    const f32x4 fz = {0.f, 0.f, 0.f, 0.f};
    f32x4 s[16];
    #pragma unroll
    for (int nt = 0; nt < 16; nt++) {
        int kr = wstart + nt * 16 + ln;
        kr = kr < 0 ? 0 : (kr > L_SEQ - 1 ? L_SEQ - 1 : kr);
        const u16* kp = F + (bbase + kr) * NF + 1024 + h * 64 + quad * 8;
        bf16x8 b0 = *(const bf16x8*)kp;
        bf16x8 b1 = *(const bf16x8*)(kp + 32);
        f32x4 t = mfma16(aq0, b0, fz);
        t = mfma16(aq1, b1, t);
        s[nt] = t;
    }

    // softmax over 256 keys; row = quad*4 + reg, col = nt*16 + ln
    float mr[4] = {-INFINITY, -INFINITY, -INFINITY, -INFINITY};
    #pragma unroll
    for (int nt = 0; nt < 16; nt++) {
        int key = wstart + nt * 16 + ln;
        bool valid = (key >= 0) && (key < L_SEQ);
        #pragma unroll
        for (int r = 0; r < 4; r++) {
            float v = valid ? s[nt][r] * 0.125f : -INFINITY;
            s[nt][r] = v;
            mr[r] = fmaxf(mr[r], v);
        }
    }
    #pragma unroll
    for (int off = 1; off < 16; off <<= 1)
        #pragma unroll
        for (int r = 0; r < 4; r++) mr[r] = fmaxf(mr[r], __shfl_xor(mr[r], off));

    float lr[4] = {0.f, 0.f, 0.f, 0.f};
    #pragma unroll
    for (int nt = 0; nt < 16; nt++)
        #pragma unroll
        for (int r = 0; r < 4; r++) {
            float p = expf(s[nt][r] - mr[r]);   // exp(-inf) = 0 on masked cols
            s[nt][r] = p;
            lr[r] += p;
        }
    #pragma unroll
    for (int off = 1; off < 16; off <<= 1)
        #pragma unroll
        for (int r = 0; r < 4; r++) lr[r] += __shfl_xor(lr[r], off);
    float rl[4];
    #pragma unroll
    for (int r = 0; r < 4; r++) rl[r] = 1.f / lr[r];

    // PV: per 32-key chunk, C-layout -> A-layout via per-wave LDS round-trip
    u16* pb = pbuf[w];
    f32x4 o[4] = {fz, fz, fz, fz};
    #pragma unroll
    for (int ks = 0; ks < 8; ks++) {
        #pragma unroll
        for (int n2 = 0; n2 < 2; n2++) {
            int nt = ks * 2 + n2;
            #pragma unroll
            for (int r = 0; r < 4; r++)
                pb[(quad * 4 + r) * 32 + n2 * 16 + ln] = f2bf(s[nt][r]);
        }
        bf16x8 ap = *(const bf16x8*)(pb + ln * 32 + quad * 8);
        #pragma unroll
        for (int dt = 0; dt < 4; dt++) {
            bf16x8 vb = *(const bf16x8*)(vT + (dt * 16 + ln) * 264 + ks * 32 + quad * 8);
            o[dt] = mfma16(ap, vb, o[dt]);
        }
    }

    // store O (row = quad*4+reg), normalized by row sum
    const int orow = blk * 128 + half * 64 + w * 16 + quad * 4;
    #pragma unroll
    for (int dt = 0; dt < 4; dt++)
        #pragma unroll
        for (int r = 0; r < 4; r++)
            AO[(bbase + orow + r) * DM + h * 64 + dt * 16 + ln] = f2bf(o[dt][r] * rl[r]);
}

// ---------------------------------------------------------------------------
extern "C" void kernel_launch(void* const* d_in, const int* in_sizes, int n_in,
                              void* d_out, int out_size, void* d_ws, size_t ws_size,
                              hipStream_t stream) {
    const float* x  = (const float*)d_in[0];
    const float* wq = (const float*)d_in[1];
    const float* wk = (const float*)d_in[2];
    const float* wv = (const float*)d_in[3];
    const float* wo = (const float*)d_in[4];
    const float* bo = (const float*)d_in[5];
    float* out = (float*)d_out;

    char* ws = (char*)d_ws;
    const size_t MB = 1024 * 1024;
    u16*   xb  = (u16*)ws;                       // 32 MB  [16384][1024] bf16
    u16*   fqkv= (u16*)(ws + 32 * MB);           // 96 MB  [16384][3072] bf16
    u16*   wf  = (u16*)(ws + 128 * MB);          // 6 MB   [3072][1024] bf16 (q,k,v stacked)
    float2* rt = (float2*)(ws + 134 * MB);       // 2 MB   [8192][32] cos/sin
    u16*   wob = (u16*)(ws + 136 * MB);          // 2 MB   [1024][1024] bf16
    u16*   aob = xb;   // x dead after fused GEMM; alias attention output over it

    cvt_bf16<<<8192, 256, 0, stream>>>(x, xb, 2097152);
    cvt_bf16<<<512, 256, 0, stream>>>(wq, wf, 131072);
    cvt_bf16<<<512, 256, 0, stream>>>(wk, wf + 1024 * 1024, 131072);
    cvt_bf16<<<512, 256, 0, stream>>>(wv, wf + 2 * 1024 * 1024, 131072);
    cvt_bf16<<<512, 256, 0, stream>>>(wo, wob, 131072);
    rope_tbl<<<1024, 256, 0, stream>>>(rt);

    gemm_qkv_fused<<<dim3(128, 24), 256, 0, stream>>>(xb, wf, rt, fqkv);
    attn<<<dim3(128, 16, 2), 256, 0, stream>>>(fqkv, aob);
    gemm_oproj<<<dim3(128, 8), 256, 0, stream>>>(aob, wob, bo, out);
}

// Round 3
// 376.236 us; speedup vs baseline: 1.5794x; 1.1786x over previous
//
#include <hip/hip_runtime.h>
#include <cstdint>
#include <math.h>

#define L_SEQ 8192
#define DM    1024
#define NQK   2048          // fused Q,K output width

typedef unsigned short u16;
typedef __bf16 bf16;
typedef bf16  bf16x8 __attribute__((ext_vector_type(8)));
typedef float f32x4  __attribute__((ext_vector_type(4)));

__device__ __forceinline__ u16 f2bf(float f) {
    unsigned u = __float_as_uint(f);
    u += 0x7fffu + ((u >> 16) & 1u);
    return (u16)(u >> 16);
}

__device__ __forceinline__ f32x4 mfma16(bf16x8 a, bf16x8 b, f32x4 c) {
    return __builtin_amdgcn_mfma_f32_16x16x32_bf16(a, b, c, 0, 0, 0);
}

__device__ __forceinline__ void gld_lds16(const u16* g, u16* l) {
    __builtin_amdgcn_global_load_lds((const __attribute__((address_space(1))) void*)g,
                                     (__attribute__((address_space(3))) void*)l,
                                     16, 0, 0);
}

// ---------------- fp32 -> bf16 conversion (8 elems / thread) ----------------
__global__ void cvt_bf16(const float* __restrict__ src, u16* __restrict__ dst, int n8) {
    int i = blockIdx.x * 256 + threadIdx.x;
    if (i >= n8) return;
    const float4* s4 = (const float4*)src;
    float4 a = s4[2 * i], b = s4[2 * i + 1];
    union { uint4 u; u16 h[8]; } r;
    r.h[0] = f2bf(a.x); r.h[1] = f2bf(a.y); r.h[2] = f2bf(a.z); r.h[3] = f2bf(a.w);
    r.h[4] = f2bf(b.x); r.h[5] = f2bf(b.y); r.h[6] = f2bf(b.z); r.h[7] = f2bf(b.w);
    ((uint4*)dst)[i] = r.u;
}

// ---------------- RoPE cos/sin table: [8192 pos][32 freq] float2 ------------
__global__ void rope_tbl(float2* __restrict__ t) {
    int idx = blockIdx.x * 256 + threadIdx.x;      // 0..262143
    int pos = idx >> 5, i = idx & 31;
    float invf = exp2f(-0.4152410118609191f * (float)i);   // 10000^(-i/32)
    float s, c;
    sincosf((float)pos * invf, &s, &c);
    t[idx] = make_float2(c, s);
}

// ---------------- Fused QKV GEMM ---------------------------------------------
// Y[m][0..2047] = (X*Wq^T | X*Wk^T) with RoPE; V slice (n0>=2048) is stored
// TRANSPOSED to Vt[(b*16+h)*64+d][seq]. 128x128 tile, BK=64, XOR-swizzled LDS.
__global__ __launch_bounds__(256) void gemm_qkv_fused(
    const u16* __restrict__ X,        // [16384][1024]
    const u16* __restrict__ W,        // [3072][1024] rows: q,k,v stacked
    const float2* __restrict__ rope,  // [8192][32]
    u16* __restrict__ Y,              // [16384][2048]
    u16* __restrict__ Vt)             // [2*16*64][8192]
{
    __shared__ __align__(16) char smem[34816];
    u16* As = (u16*)smem;          // [128][64] swizzled
    u16* Bs = As + 128 * 64;       // [128][64] swizzled

    const int n0 = blockIdx.x * 128;   // n fastest -> X tile L2-hot
    const int m0 = blockIdx.y * 128;
    const int tid = threadIdx.x;
    const int lane = tid & 63, wid = tid >> 6;
    const int wm = wid >> 1, wn = wid & 1;
    const int quad = lane >> 4, ln = lane & 15;

    const f32x4 fz = {0.f, 0.f, 0.f, 0.f};
    f32x4 acc[4][4];
    for (int a = 0; a < 4; a++)
        for (int b = 0; b < 4; b++) acc[a][b] = fz;

    for (int k0 = 0; k0 < DM; k0 += 64) {
        __syncthreads();
        #pragma unroll
        for (int i = 0; i < 4; ++i) {
            int idx = i * 256 + tid;
            int row = idx >> 3, cl = idx & 7;
            int cg = cl ^ (row & 7);
            gld_lds16(X + (size_t)(m0 + row) * DM + k0 + cg * 8, As + idx * 8);
            gld_lds16(W + (size_t)(n0 + row) * DM + k0 + cg * 8, Bs + idx * 8);
        }
        __syncthreads();
        #pragma unroll
        for (int ks = 0; ks < 2; ks++) {
            bf16x8 af[4], bfr[4];
            #pragma unroll
            for (int t = 0; t < 4; t++) {
                int ra = wm * 64 + t * 16 + ln;
                af[t]  = *(const bf16x8*)(As + ra * 64 + (((ks * 4 + quad) ^ (ln & 7)) * 8));
                int rb = wn * 64 + t * 16 + ln;
                bfr[t] = *(const bf16x8*)(Bs + rb * 64 + (((ks * 4 + quad) ^ (ln & 7)) * 8));
            }
            #pragma unroll
            for (int mt = 0; mt < 4; mt++)
                #pragma unroll
                for (int nt = 0; nt < 4; nt++)
                    acc[mt][nt] = mfma16(af[mt], bfr[nt], acc[mt][nt]);
        }
    }
    __syncthreads();

    if (n0 < 2048) {
        // RoPE (table). Wave covers one head's 64 cols; pair (i,i+32) = tiles (nt,nt+2).
        #pragma unroll
        for (int mt = 0; mt < 4; mt++)
            #pragma unroll
            for (int reg = 0; reg < 4; reg++) {
                int rg = (m0 + wm * 64 + mt * 16 + quad * 4 + reg) & (L_SEQ - 1);
                const float2* rp = rope + rg * 32;
                #pragma unroll
                for (int nt = 0; nt < 2; nt++) {
                    float2 cs = rp[nt * 16 + ln];
                    float x1 = acc[mt][nt][reg], x2 = acc[mt][nt + 2][reg];
                    acc[mt][nt][reg]     = x1 * cs.x - x2 * cs.y;
                    acc[mt][nt + 2][reg] = x2 * cs.x + x1 * cs.y;
                }
            }
        // row-major bf16 epilogue -> Y
        u16* Es = (u16*)smem;   // [128][136]
        #pragma unroll
        for (int mt = 0; mt < 4; mt++)
            #pragma unroll
            for (int nt = 0; nt < 4; nt++)
                #pragma unroll
                for (int reg = 0; reg < 4; reg++) {
                    int rl = wm * 64 + mt * 16 + quad * 4 + reg;
                    int cl = wn * 64 + nt * 16 + ln;
                    Es[rl * 136 + cl] = f2bf(acc[mt][nt][reg]);
                }
        __syncthreads();
        #pragma unroll
        for (int i = 0; i < 8; i++) {
            int idx = i * 256 + tid;
            int row = idx >> 4, ch = (idx & 15) * 8;
            uint4 v = *(const uint4*)(Es + row * 136 + ch);
            *(uint4*)(Y + (size_t)(m0 + row) * NQK + n0 + ch) = v;
        }
    } else {
        // V slice: store TRANSPOSED.  Es[col][row]: col=dim-local, row=seq-local.
        u16* Es = (u16*)smem;   // [128 cols][136]
        #pragma unroll
        for (int mt = 0; mt < 4; mt++)
            #pragma unroll
            for (int nt = 0; nt < 4; nt++)
                #pragma unroll
                for (int reg = 0; reg < 4; reg++) {
                    int rl = wm * 64 + mt * 16 + quad * 4 + reg;
                    int cl = wn * 64 + nt * 16 + ln;
                    Es[cl * 136 + rl] = f2bf(acc[mt][nt][reg]);
                }
        __syncthreads();
        const int bb = m0 >> 13, seq0 = m0 & (L_SEQ - 1);
        #pragma unroll
        for (int i = 0; i < 8; i++) {
            int idx = i * 256 + tid;
            int dr = idx >> 4, ch = (idx & 15) * 8;
            uint4 v = *(const uint4*)(Es + dr * 136 + ch);
            int gc = n0 - 2048 + dr;        // global V col = h*64 + d
            *(uint4*)(Vt + (size_t)(bb * 1024 + gc) * L_SEQ + seq0 + ch) = v;
        }
    }
}

// ---------------- Output projection: Out = A * Wo^T + bo, fp32 out ----------
__global__ __launch_bounds__(256) void gemm_oproj(
    const u16* __restrict__ A,        // [16384][1024] bf16
    const u16* __restrict__ Wo,       // [1024][1024] bf16
    const float* __restrict__ bias,
    float* __restrict__ Out)
{
    __shared__ __align__(16) char smem[34816];
    u16* As = (u16*)smem;
    u16* Bs = As + 128 * 64;

    const int n0 = blockIdx.x * 128;
    const int m0 = blockIdx.y * 128;
    const int tid = threadIdx.x;
    const int lane = tid & 63, wid = tid >> 6;
    const int wm = wid >> 1, wn = wid & 1;
    const int quad = lane >> 4, ln = lane & 15;

    const f32x4 fz = {0.f, 0.f, 0.f, 0.f};
    f32x4 acc[4][4];
    for (int a = 0; a < 4; a++)
        for (int b = 0; b < 4; b++) acc[a][b] = fz;

    for (int k0 = 0; k0 < DM; k0 += 64) {
        __syncthreads();
        #pragma unroll
        for (int i = 0; i < 4; ++i) {
            int idx = i * 256 + tid;
            int row = idx >> 3, cl = idx & 7;
            int cg = cl ^ (row & 7);
            gld_lds16(A  + (size_t)(m0 + row) * DM + k0 + cg * 8, As + idx * 8);
            gld_lds16(Wo + (size_t)(n0 + row) * DM + k0 + cg * 8, Bs + idx * 8);
        }
        __syncthreads();
        #pragma unroll
        for (int ks = 0; ks < 2; ks++) {
            bf16x8 af[4], bfr[4];
            #pragma unroll
            for (int t = 0; t < 4; t++) {
                int ra = wm * 64 + t * 16 + ln;
                af[t]  = *(const bf16x8*)(As + ra * 64 + (((ks * 4 + quad) ^ (ln & 7)) * 8));
                int rb = wn * 64 + t * 16 + ln;
                bfr[t] = *(const bf16x8*)(Bs + rb * 64 + (((ks * 4 + quad) ^ (ln & 7)) * 8));
            }
            #pragma unroll
            for (int mt = 0; mt < 4; mt++)
                #pragma unroll
                for (int nt = 0; nt < 4; nt++)
                    acc[mt][nt] = mfma16(af[mt], bfr[nt], acc[mt][nt]);
        }
    }

    float* Ef = (float*)smem;
    for (int hh = 0; hh < 2; ++hh) {
        __syncthreads();
        if (wm == hh) {
            #pragma unroll
            for (int mt = 0; mt < 4; mt++)
                #pragma unroll
                for (int nt = 0; nt < 4; nt++)
                    #pragma unroll
                    for (int reg = 0; reg < 4; reg++) {
                        int rl = mt * 16 + quad * 4 + reg;
                        int cl = wn * 64 + nt * 16 + ln;
                        Ef[rl * 136 + cl] = acc[mt][nt][reg] + bias[n0 + cl];
                    }
        }
        __syncthreads();
        #pragma unroll
        for (int i = 0; i < 8; i++) {
            int idx = i * 256 + tid;
            int row = idx >> 5, ch = (idx & 31) * 4;
            float4 v = *(const float4*)(Ef + row * 136 + ch);
            *(float4*)(Out + (size_t)(m0 + hh * 64 + row) * DM + n0 + ch) = v;
        }
    }
}

// ---------------- Windowed attention ----------------------------------------
// WG = 512 threads / 8 waves = 128 queries x 1 head. grid (64, 16, 2).
// K and V^T staged once per WG via global_load_lds (XOR chunk swizzle).
__global__ __launch_bounds__(512, 4) void attn(
    const u16* __restrict__ QK,       // [16384][2048]
    const u16* __restrict__ Vt,       // [2048][8192]
    u16* __restrict__ AO)             // [16384][1024]
{
    __shared__ __align__(16) u16 Ks[256 * 64];     // [key][dim-chunk swizzled] 32KB (aliased by AOs)
    __shared__ __align__(16) u16 Vs[64 * 256];     // [dim][key-chunk swizzled] 32KB
    __shared__ __align__(16) u16 pbuf[8][512];     // per-wave P chunk, xor-swizzled

    const int blk = blockIdx.x;
    const int h   = blockIdx.y;
    const int b   = blockIdx.z;
    const int tid = threadIdx.x;
    const int lane = tid & 63, w = tid >> 6;
    const int quad = lane >> 4, ln = lane & 15;
    const int wstart = blk * 128 - 64;
    const size_t bbase = (size_t)b * L_SEQ;

    const u16* Kg = QK + 1024 + h * 64;
    const u16* Vg = Vt + (size_t)(b * 1024 + h * 64) * L_SEQ;

    // stage K: 256 rows x 8 chunks, chunk cg = cl ^ (row&7)
    #pragma unroll
    for (int i = 0; i < 4; i++) {
        int c = i * 512 + tid;
        int row = c >> 3, cl = c & 7, cg = cl ^ (row & 7);
        int kr = wstart + row;
        kr = kr < 0 ? 0 : (kr > L_SEQ - 1 ? L_SEQ - 1 : kr);
        gld_lds16(Kg + (size_t)(bbase + kr) * NQK + cg * 8, Ks + c * 8);
    }
    // stage V^T: 64 dim-rows x 32 key-chunks, chunk cg = kc ^ (d&7)
    #pragma unroll
    for (int i = 0; i < 4; i++) {
        int c = i * 512 + tid;
        int d = c >> 5, kc = c & 31, cg = kc ^ (d & 7);
        int key = wstart + cg * 8;
        key = key < 0 ? 0 : (key > L_SEQ - 8 ? L_SEQ - 8 : key);
        gld_lds16(Vg + (size_t)d * L_SEQ + key, Vs + c * 8);
    }

    // Q fragments (A-layout: m=ln, k=quad*8+j) direct from global
    const int qrow = blk * 128 + w * 16 + ln;
    const u16* qp = QK + (bbase + qrow) * NQK + h * 64 + quad * 8;
    bf16x8 aq0 = *(const bf16x8*)qp;
    bf16x8 aq1 = *(const bf16x8*)(qp + 32);
    __syncthreads();

    // scores: 16 n-tiles x 16 keys
    const f32x4 fz = {0.f, 0.f, 0.f, 0.f};
    f32x4 s[16];
    #pragma unroll
    for (int nt = 0; nt < 16; nt++) {
        int row = nt * 16 + ln;
        bf16x8 b0 = *(const bf16x8*)(Ks + row * 64 + ((quad       ^ (ln & 7)) * 8));
        bf16x8 b1 = *(const bf16x8*)(Ks + row * 64 + (((4 + quad) ^ (ln & 7)) * 8));
        f32x4 t = mfma16(aq0, b0, fz);
        t = mfma16(aq1, b1, t);
        s[nt] = t;
    }
    __syncthreads();   // all Ks reads done before AOs (alias) writes

    // softmax; row = quad*4+r, col key = wstart + nt*16 + ln
    const float SC = 0.125f * 1.4426950408889634f;   // /sqrt(64) * log2(e)
    float mr[4] = {-INFINITY, -INFINITY, -INFINITY, -INFINITY};
    #pragma unroll
    for (int nt = 0; nt < 16; nt++) {
        int key = wstart + nt * 16 + ln;
        bool valid = (key >= 0) && (key < L_SEQ);
        #pragma unroll
        for (int r = 0; r < 4; r++) {
            float v = valid ? s[nt][r] * SC : -INFINITY;
            s[nt][r] = v;
            mr[r] = fmaxf(mr[r], v);
        }
    }
    #pragma unroll
    for (int off = 1; off < 16; off <<= 1)
        #pragma unroll
        for (int r = 0; r < 4; r++) mr[r] = fmaxf(mr[r], __shfl_xor(mr[r], off));

    float lr[4] = {0.f, 0.f, 0.f, 0.f};
    #pragma unroll
    for (int nt = 0; nt < 16; nt++)
        #pragma unroll
        for (int r = 0; r < 4; r++) {
            float p = exp2f(s[nt][r] - mr[r]);   // exp2(-inf)=0 on masked cols
            s[nt][r] = p;
            lr[r] += p;
        }
    #pragma unroll
    for (int off = 1; off < 16; off <<= 1)
        #pragma unroll
        for (int r = 0; r < 4; r++) lr[r] += __shfl_xor(lr[r], off);
    float rl[4];
    #pragma unroll
    for (int r = 0; r < 4; r++) rl[r] = 1.f / lr[r];

    // PV: per 32-key chunk, C-layout -> A-layout via xor-swizzled per-wave LDS
    u16* pb = pbuf[w];
    f32x4 o[4] = {fz, fz, fz, fz};
    #pragma unroll
    for (int ks = 0; ks < 8; ks++) {
        #pragma unroll
        for (int n2 = 0; n2 < 2; n2++) {
            int nt = ks * 2 + n2;
            #pragma unroll
            for (int r = 0; r < 4; r++)
                pb[(quad * 4 + r) * 32 + ((n2 * 16 + ln) ^ (quad * 8))] = f2bf(s[nt][r]);
        }
        bf16x8 ap = *(const bf16x8*)(pb + ln * 32 + ((quad * 8) ^ (((ln >> 2) & 3) * 8)));
        #pragma unroll
        for (int dt = 0; dt < 4; dt++) {
            int d = dt * 16 + ln;
            bf16x8 vb = *(const bf16x8*)(Vs + d * 256 + (((ks * 4 + quad) ^ (ln & 7)) * 8));
            o[dt] = mfma16(ap, vb, o[dt]);
        }
    }

    // AO through LDS (alias Ks) for coalesced 16B stores
    u16* AOs = Ks;   // [128][72]
    #pragma unroll
    for (int dt = 0; dt < 4; dt++)
        #pragma unroll
        for (int r = 0; r < 4; r++)
            AOs[(w * 16 + quad * 4 + r) * 72 + dt * 16 + ln] = f2bf(o[dt][r] * rl[r]);
    __syncthreads();
    #pragma unroll
    for (int i = 0; i < 2; i++) {
        int c = i * 512 + tid;
        int row = c >> 3, ch = (c & 7) * 8;
        uint4 v = *(const uint4*)(AOs + row * 72 + ch);
        *(uint4*)(AO + (bbase + blk * 128 + row) * DM + h * 64 + ch) = v;
    }
}

// ---------------------------------------------------------------------------
extern "C" void kernel_launch(void* const* d_in, const int* in_sizes, int n_in,
                              void* d_out, int out_size, void* d_ws, size_t ws_size,
                              hipStream_t stream) {
    const float* x  = (const float*)d_in[0];
    const float* wq = (const float*)d_in[1];
    const float* wk = (const float*)d_in[2];
    const float* wv = (const float*)d_in[3];
    const float* wo = (const float*)d_in[4];
    const float* bo = (const float*)d_in[5];
    float* out = (float*)d_out;

    char* ws = (char*)d_ws;
    const size_t MB = 1024 * 1024;
    u16*   xb  = (u16*)ws;                       // 32 MB  [16384][1024] bf16
    u16*   fqk = (u16*)(ws + 32 * MB);           // 64 MB  [16384][2048] bf16 (Q|K)
    u16*   vt  = (u16*)(ws + 96 * MB);           // 32 MB  [2048][8192] bf16 (V^T)
    u16*   wf  = (u16*)(ws + 128 * MB);          // 6 MB   [3072][1024] bf16 (q,k,v stacked)
    float2* rt = (float2*)(ws + 134 * MB);       // 2 MB   [8192][32] cos/sin
    u16*   wob = (u16*)(ws + 136 * MB);          // 2 MB   [1024][1024] bf16
    u16*   aob = xb;   // x dead after fused GEMM; alias attention output over it

    cvt_bf16<<<8192, 256, 0, stream>>>(x, xb, 2097152);
    cvt_bf16<<<512, 256, 0, stream>>>(wq, wf, 131072);
    cvt_bf16<<<512, 256, 0, stream>>>(wk, wf + 1024 * 1024, 131072);
    cvt_bf16<<<512, 256, 0, stream>>>(wv, wf + 2 * 1024 * 1024, 131072);
    cvt_bf16<<<512, 256, 0, stream>>>(wo, wob, 131072);
    rope_tbl<<<1024, 256, 0, stream>>>(rt);

    gemm_qkv_fused<<<dim3(24, 128), 256, 0, stream>>>(xb, wf, rt, fqk, vt);
    attn<<<dim3(64, 16, 2), 512, 0, stream>>>(fqk, vt, aob);
    gemm_oproj<<<dim3(8, 128), 256, 0, stream>>>(aob, wob, bo, out);
}